// Round 9
// baseline (261.737 us; speedup 1.0000x reference)
//
#include <hip/hip_runtime.h>

#define NF 256        // features
#define NT 4096       // time steps
#define NB 64         // batch
#define CHUNKS 16     // time chunks per batch (reduce)
#define TPC (NT / CHUNKS)     // 256 rows per chunk
#define NQ 4          // quarters
#define BPQ (NB / NQ)         // 16 batches per quarter
#define EPS 1e-5f
#define PAD 32        // ints per control slot -> 128 B apart

typedef float vfloat4 __attribute__((ext_vector_type(4)));

__device__ __forceinline__ float fast_tanh(float v) {
    float e = __expf(2.0f * v);                        // inf/0 endpoints -> +-1
    return 1.0f - 2.0f * __builtin_amdgcn_rcpf(e + 1.0f);
}

// ---------------------------------------------------------------------------
// RS kernel: quarter q. 256 blocks = 16 batches x 16 chunks.
// Each block: partial sum/sumsq of its 256-row chunk (pure HBM read).
// Last-arriver per batch: chunk-reduce + MLP -> sA/cA. No block ever waits.
// Kernel boundary (implicit device release) publishes sA/cA to A(q).
// ---------------------------------------------------------------------------
__global__ __launch_bounds__(256) void k_rs(
    const float* __restrict__ x, int q,
    const float* __restrict__ W1, const float* __restrict__ b1,
    const float* __restrict__ W2, const float* __restrict__ b2,
    float* __restrict__ partial, float* __restrict__ sA, float* __restrict__ cA,
    int* __restrict__ cnt)
{
    const int blk = blockIdx.x;
    const int b   = q * BPQ + (blk >> 4);   // global batch
    const int c   = blk & 15;               // chunk
    const int tid = threadIdx.x;
    const int qd  = tid & 63;                // float4 slot within a feature row
    const int g   = tid >> 6;                // row group 0..3

    // ---- partial sum / sumsq over this chunk's 256 rows -------------------
    const float4* __restrict__ xrow =
        (const float4*)(x + ((size_t)b * NT + (size_t)c * TPC) * NF);

    float4 s  = {0.f, 0.f, 0.f, 0.f};
    float4 ss = {0.f, 0.f, 0.f, 0.f};
    #pragma unroll 8
    for (int t = g; t < TPC; t += 4) {
        float4 v = xrow[t * (NF / 4) + qd];
        s.x += v.x; s.y += v.y; s.z += v.z; s.w += v.w;
        ss.x = fmaf(v.x, v.x, ss.x);
        ss.y = fmaf(v.y, v.y, ss.y);
        ss.z = fmaf(v.z, v.z, ss.z);
        ss.w = fmaf(v.w, v.w, ss.w);
    }

    __shared__ float4 smS[4][64];
    __shared__ float4 smQ[4][64];
    smS[g][qd] = s;
    smQ[g][qd] = ss;
    __syncthreads();

    const float* sS = (const float*)smS;
    const float* sQ = (const float*)smQ;
    float sum = sS[0 * NF + tid] + sS[1 * NF + tid] + sS[2 * NF + tid] + sS[3 * NF + tid];
    float sq  = sQ[0 * NF + tid] + sQ[1 * NF + tid] + sQ[2 * NF + tid] + sQ[3 * NF + tid];

    float* p = partial + (size_t)(b * CHUNKS + c) * 2 * NF;
    p[tid]      = sum;
    p[NF + tid] = sq;
    __syncthreads();                     // all partial stores issued

    __shared__ int isLast;
    if (tid == 0) {
        // RELEASE: make our partials visible before the count ticks.
        int old = __hip_atomic_fetch_add(&cnt[b * PAD], 1, __ATOMIC_RELEASE,
                                         __HIP_MEMORY_SCOPE_AGENT);
        isLast = (old == CHUNKS - 1);
    }
    __syncthreads();
    if (!isLast) return;                 // non-last blocks exit immediately

    // ---- last-arriver: stats + MLP + fold constants ------------------------
    if (tid == 0)                        // one acquire to see siblings' partials
        (void)__hip_atomic_load(&cnt[b * PAD], __ATOMIC_ACQUIRE,
                                __HIP_MEMORY_SCOPE_AGENT);
    __syncthreads();

    const int f = tid;
    float tsum = 0.f, tsq = 0.f;
    #pragma unroll
    for (int cc = 0; cc < CHUNKS; ++cc) {
        const float* pp = partial + (size_t)(b * CHUNKS + cc) * 2 * NF;
        tsum += pp[f];
        tsq  += pp[NF + f];
    }
    const float mean = tsum * (1.0f / NT);
    float var = fmaxf(tsq * (1.0f / NT) - mean * mean, 0.0f);
    const float stdv = sqrtf(var + EPS);

    __shared__ float stats[2 * NF];
    __shared__ float h[NF];
    stats[f]      = mean;
    stats[NF + f] = stdv;
    __syncthreads();

    float acc = b1[f];
    const float* w1r = W1 + (size_t)f * (2 * NF);
    #pragma unroll 8
    for (int k = 0; k < 2 * NF; ++k) acc = fmaf(stats[k], w1r[k], acc);
    h[f] = fmaxf(acc, 0.0f);
    __syncthreads();

    float acc2 = b2[f];
    const float* w2r = W2 + (size_t)f * NF;
    #pragma unroll 8
    for (int k = 0; k < NF; ++k) acc2 = fmaf(h[k], w2r[k], acc2);
    const float alpha = 1.0f / (1.0f + __expf(-acc2));

    const float sv = alpha / stdv;
    sA[b * NF + f] = sv;                 // plain stores; kernel end publishes
    cA[b * NF + f] = -mean * sv;
}

// ---------------------------------------------------------------------------
// A kernel: apply on quarter q. 1024 blocks x 256 threads x 16 float4.
// x reads should hit L3 (just streamed by RS(q)); NT stores -> HBM.
// ---------------------------------------------------------------------------
__global__ __launch_bounds__(256) void k_apply(
    const float4* __restrict__ x, int q,
    const float* __restrict__ sA, const float* __restrict__ cA,
    const float4* __restrict__ gamma, const float4* __restrict__ beta,
    float4* __restrict__ out)
{
    const int blk = blockIdx.x;
    const int b   = q * BPQ + (blk >> 6);   // 64 blocks per batch
    const int seg = blk & 63;
    const int tid = threadIdx.x;
    const int fq  = tid & 63;               // float4 slot within feature row

    const float4 s4 = ((const float4*)sA)[b * 64 + fq];
    const float4 c4 = ((const float4*)cA)[b * 64 + fq];
    const float4 g4 = gamma[fq];
    const float4 t4 = beta[fq];

    const size_t base = (size_t)b * 262144 + (size_t)seg * 4096 + tid; // float4
    const float4* __restrict__ xp = x + base;
    vfloat4* __restrict__ op = (vfloat4*)(out + base);

    #pragma unroll 4
    for (int k = 0; k < 16; ++k) {
        float4 v = xp[k * 256];
        vfloat4 o;
        o.x = fmaf(g4.x, fast_tanh(fmaf(v.x, s4.x, c4.x)), t4.x);
        o.y = fmaf(g4.y, fast_tanh(fmaf(v.y, s4.y, c4.y)), t4.y);
        o.z = fmaf(g4.z, fast_tanh(fmaf(v.z, s4.z, c4.z)), t4.z);
        o.w = fmaf(g4.w, fast_tanh(fmaf(v.w, s4.w, c4.w)), t4.w);
        __builtin_nontemporal_store(o, &op[k * 256]);
    }
}

extern "C" void kernel_launch(void* const* d_in, const int* in_sizes, int n_in,
                              void* d_out, int out_size, void* d_ws, size_t ws_size,
                              hipStream_t stream) {
    const float* x     = (const float*)d_in[0];
    const float* gamma = (const float*)d_in[1];
    const float* beta  = (const float*)d_in[2];
    const float* W1    = (const float*)d_in[3];
    const float* b1    = (const float*)d_in[4];
    const float* W2    = (const float*)d_in[5];
    const float* b2    = (const float*)d_in[6];
    float* out = (float*)d_out;

    float* ws      = (float*)d_ws;
    float* partial = ws;                                   // 64*16*512 f = 2 MB
    float* sA      = ws + (size_t)NB * CHUNKS * 2 * NF;    // 64 KB
    float* cA      = sA + NB * NF;                         // 64 KB
    int*   cnt     = (int*)(cA + NB * NF);                 // 64*32 ints = 8 KB

    hipMemsetAsync(cnt, 0, NB * PAD * sizeof(int), stream);

    for (int q = 0; q < NQ; ++q) {
        k_rs<<<BPQ * CHUNKS, 256, 0, stream>>>(x, q, W1, b1, W2, b2,
                                               partial, sA, cA, cnt);
        k_apply<<<BPQ * 64, 256, 0, stream>>>((const float4*)x, q, sA, cA,
                                              (const float4*)gamma,
                                              (const float4*)beta,
                                              (float4*)out);
    }
}